// Round 1
// baseline (632.526 us; speedup 1.0000x reference)
//
#include <hip/hip_runtime.h>
#include <stdint.h>

// Shapes (fixed by the problem)
#define BB 2
#define SS 2048
#define HID 1024
#define NHEAD 16
#define DHEAD 64
#define MTOT (BB*SS)          // 4096 tokens

typedef float  f32x4  __attribute__((ext_vector_type(4)));
typedef short  s16x8  __attribute__((ext_vector_type(8)));
typedef unsigned short u16x4 __attribute__((ext_vector_type(4)));

#define LOG2E 1.4426950408889634f

// round-to-nearest-even f32 -> bf16 (bit pattern)
__device__ __forceinline__ unsigned short f2bf(float x){
  union { float f; unsigned u; } v; v.f = x;
  unsigned r = v.u + 0x7fffu + ((v.u >> 16) & 1u);
  return (unsigned short)(r >> 16);
}

// async global->LDS, 16 bytes per lane (dest must be wave-uniform base + lane*16)
__device__ __forceinline__ void gl2lds16(const unsigned short* g, unsigned short* l){
  __builtin_amdgcn_global_load_lds((const __attribute__((address_space(1))) void*)g,
                                   (__attribute__((address_space(3))) void*)l, 16, 0, 0);
}

// ---------------------------------------------------------------------------
// 1) hidden_states f32 -> bf16 (row-major [4096][1024])
// ---------------------------------------------------------------------------
__global__ __launch_bounds__(256) void k_convert_x(const float* __restrict__ x,
                                                   unsigned short* __restrict__ xb){
  int i = blockIdx.x * 256 + threadIdx.x;   // one float4 per thread
  const float4* xp = (const float4*)x;
  float4 v = xp[i];
  u16x4 o; o.x = f2bf(v.x); o.y = f2bf(v.y); o.z = f2bf(v.z); o.w = f2bf(v.w);
  ((u16x4*)xb)[i] = o;
}

// ---------------------------------------------------------------------------
// 2) weights f32 [K][N] -> bf16 transposed [N][K] (Wq,Wk,Wv -> Wt rows 0..3071; Wo -> Wot)
// ---------------------------------------------------------------------------
__global__ __launch_bounds__(256) void k_convert_w(const float* __restrict__ Wq,
                                                   const float* __restrict__ Wk,
                                                   const float* __restrict__ Wv,
                                                   const float* __restrict__ Wo,
                                                   unsigned short* __restrict__ Wt,
                                                   unsigned short* __restrict__ Wot){
  __shared__ float tile[64][65];
  int z = blockIdx.z;
  const float* src = (z==0) ? Wq : (z==1) ? Wk : (z==2) ? Wv : Wo;
  unsigned short* dst = (z < 3) ? (Wt + z * HID * HID) : Wot;
  int n0 = blockIdx.x * 64, k0 = blockIdx.y * 64;
  int t = threadIdx.x, tx = t & 63, ty = t >> 6;
  #pragma unroll
  for (int i = 0; i < 16; i++){
    int kl = ty + i*4;
    tile[kl][tx] = src[(k0 + kl) * HID + n0 + tx];
  }
  __syncthreads();
  #pragma unroll
  for (int i = 0; i < 16; i++){
    int nl = ty + i*4;
    dst[(n0 + nl) * HID + k0 + tx] = f2bf(tile[tx][nl]);
  }
}

// ---------------------------------------------------------------------------
// 3) QKV GEMM: Xb[4096][1024] @ Wt[3072][1024]^T -> Qb (x0.125), Kb, Vt (transposed per head)
//    m97 structure: 128x128 tile, BK=32, 4 waves in 2x2, 16 MFMA/wave/k-step
// ---------------------------------------------------------------------------
__global__ __launch_bounds__(256) void k_gemm_qkv(const unsigned short* __restrict__ A,
                                                  const unsigned short* __restrict__ Bt,
                                                  unsigned short* __restrict__ Qb,
                                                  unsigned short* __restrict__ Kb,
                                                  unsigned short* __restrict__ Vt){
  __shared__ __align__(16) unsigned short As[128*32];
  __shared__ __align__(16) unsigned short Bs[128*32];
  int t = threadIdx.x;
  int L = t & 63, w = t >> 6;
  int q = L >> 4, c = L & 15;
  int m0 = blockIdx.x * 128, n0 = blockIdx.y * 128;
  int wr = w >> 1, wc = w & 1;
  f32x4 acc[4][4];
  #pragma unroll
  for (int i = 0; i < 4; i++)
    #pragma unroll
    for (int j = 0; j < 4; j++) acc[i][j] = (f32x4){0.f,0.f,0.f,0.f};

  for (int kb = 0; kb < 32; kb++){
    __syncthreads();
    #pragma unroll
    for (int i = 0; i < 2; i++){
      int p = t + i*256;                // 512 chunks of 16B per tile
      int row = p >> 2, cp = p & 3;     // [128 rows][4 chunks]
      gl2lds16(A  + (m0 + row) * HID + kb*32 + cp*8, As + p*8);
      gl2lds16(Bt + (n0 + row) * HID + kb*32 + cp*8, Bs + p*8);
    }
    __syncthreads();
    s16x8 af[4], bf[4];
    #pragma unroll
    for (int i = 0; i < 4; i++){
      int m = wr*64 + i*16 + c;
      af[i] = *(const s16x8*)(As + m*32 + q*8);
      int n = wc*64 + i*16 + c;
      bf[i] = *(const s16x8*)(Bs + n*32 + q*8);
    }
    #pragma unroll
    for (int i = 0; i < 4; i++)
      #pragma unroll
      for (int j = 0; j < 4; j++)
        acc[i][j] = __builtin_amdgcn_mfma_f32_16x16x32_bf16(af[i], bf[j], acc[i][j], 0, 0, 0);
  }

  int wsel = n0 >> 10;                  // 0=Q, 1=K, 2=V (128 | 1024, never straddles)
  #pragma unroll
  for (int i = 0; i < 4; i++){
    #pragma unroll
    for (int j = 0; j < 4; j++){
      int m_l = wr*64 + i*16 + q*4;
      int n_g = n0 + wc*64 + j*16 + c;
      int nw  = n_g & 1023;
      if (wsel == 0){
        #pragma unroll
        for (int r = 0; r < 4; r++)
          Qb[(m0 + m_l + r) * HID + nw] = f2bf(acc[i][j][r] * 0.125f);  // fold 1/sqrt(64)
      } else if (wsel == 1){
        #pragma unroll
        for (int r = 0; r < 4; r++)
          Kb[(m0 + m_l + r) * HID + nw] = f2bf(acc[i][j][r]);
      } else {
        int tok = m0 + m_l;
        int b = tok >> 11, s = tok & 2047;
        int h = nw >> 6, d = nw & 63;
        u16x4 pk;
        pk.x = f2bf(acc[i][j][0]); pk.y = f2bf(acc[i][j][1]);
        pk.z = f2bf(acc[i][j][2]); pk.w = f2bf(acc[i][j][3]);
        *(u16x4*)(Vt + (((b*NHEAD + h)*DHEAD + d) * (size_t)SS + s)) = pk; // Vt[b][h][d][s]
      }
    }
  }
}

// ---------------------------------------------------------------------------
// 4) Flash attention: per (qt, b*h) block of 64 Q rows; online softmax; causal;
//    ALiBi computed analytically; tanh softcap at 30. Writes ctx bf16 [tok][h*64+d].
// ---------------------------------------------------------------------------
__global__ __launch_bounds__(256) void k_attn(const unsigned short* __restrict__ Qb,
                                              const unsigned short* __restrict__ Kb,
                                              const unsigned short* __restrict__ Vt,
                                              const int* __restrict__ amask,
                                              unsigned short* __restrict__ ctx){
  __shared__ __align__(16) unsigned short Qs[64*64];
  __shared__ __align__(16) unsigned short Ks[64*64];
  __shared__ __align__(16) unsigned short Vs[64*64];
  __shared__ __align__(16) unsigned short Ps[4][16*72];   // per-wave P tile, stride 72 (144B)

  int t = threadIdx.x;
  int L = t & 63, w = t >> 6;
  int q = L >> 4, c = L & 15;
  int qt = 31 - (int)blockIdx.x;        // big (late) q-tiles first -> better tail
  int bh = blockIdx.y;
  int b = bh >> 4, h = bh & 15;
  int i0 = qt * 64;

  // ALiBi slope * 0.125 (exact): slope = 2^{-(h+1)/2}
  int hp = h + 1;
  float slope = (hp & 1) ? 0.70710678118654752f : 1.0f;
  slope = ldexpf(slope, -((hp >> 1) + 3));   // includes the /8 fold

  // stage Q tile [64 rows][64 d], XOR chunk swizzle (chunk ^= row&7)
  #pragma unroll
  for (int i = 0; i < 2; i++){
    int p = t + i*256; int row = p >> 3, cp = p & 7; int gc = cp ^ (row & 7);
    gl2lds16(Qb + (size_t)(b*SS + i0 + row) * HID + h*DHEAD + gc*8, Qs + p*8);
  }
  __syncthreads();
  s16x8 qf0, qf1;
  {
    int m = w*16 + c;
    qf0 = *(const s16x8*)(Qs + m*64 + ((0 + q) ^ (m & 7)) * 8);
    qf1 = *(const s16x8*)(Qs + m*64 + ((4 + q) ^ (m & 7)) * 8);
  }

  f32x4 cacc[4];
  #pragma unroll
  for (int i = 0; i < 4; i++) cacc[i] = (f32x4){0.f,0.f,0.f,0.f};
  float mrow[4] = {-1e30f,-1e30f,-1e30f,-1e30f};
  float lrow[4] = {0.f,0.f,0.f,0.f};

  for (int jt = 0; jt <= qt; jt++){
    int j0 = jt * 64;
    __syncthreads();                 // all waves done reading last K/V tiles
    #pragma unroll
    for (int i = 0; i < 2; i++){
      int p = t + i*256; int row = p >> 3, cp = p & 7; int gc = cp ^ (row & 7);
      gl2lds16(Kb + (size_t)(b*SS + j0 + row) * HID + h*DHEAD + gc*8, Ks + p*8);
      gl2lds16(Vt + (size_t)(bh*DHEAD + row) * SS + j0 + gc*8, Vs + p*8);
    }
    __syncthreads();

    // S = Q K^T  (rows: this wave's 16; cols: 64)
    f32x4 sacc[4];
    #pragma unroll
    for (int ct = 0; ct < 4; ct++){
      int n = ct*16 + c;
      s16x8 kf0 = *(const s16x8*)(Ks + n*64 + ((0 + q) ^ (n & 7)) * 8);
      s16x8 kf1 = *(const s16x8*)(Ks + n*64 + ((4 + q) ^ (n & 7)) * 8);
      f32x4 z = (f32x4){0.f,0.f,0.f,0.f};
      z = __builtin_amdgcn_mfma_f32_16x16x32_bf16(qf0, kf0, z, 0, 0, 0);
      z = __builtin_amdgcn_mfma_f32_16x16x32_bf16(qf1, kf1, z, 0, 0, 0);
      sacc[ct] = z;
    }

    // scores: + alibi, softcap 30*tanh(s/30), causal+pad mask
    float p_[4][4];
    #pragma unroll
    for (int ct = 0; ct < 4; ct++){
      int jg = j0 + ct*16 + c;
      int pad = amask[b*SS + jg];
      #pragma unroll
      for (int r = 0; r < 4; r++){
        int ig = i0 + w*16 + q*4 + r;
        float s = sacc[ct][r] + slope * (float)(jg - ig);
        float e = exp2f(s * (2.0f * LOG2E / 30.0f));       // e^{2s/30}
        s = 30.0f * (e - 1.0f) / (e + 1.0f);               // 30*tanh(s/30)
        bool ok = (jg <= ig) && (pad != 0);
        p_[ct][r] = ok ? s : -1e30f;
      }
    }

    // online softmax (row = q*4 + r, spread over 16 lanes of the quad)
    #pragma unroll
    for (int r = 0; r < 4; r++){
      float tm = fmaxf(fmaxf(p_[0][r], p_[1][r]), fmaxf(p_[2][r], p_[3][r]));
      tm = fmaxf(tm, __shfl_xor(tm, 1, 64));
      tm = fmaxf(tm, __shfl_xor(tm, 2, 64));
      tm = fmaxf(tm, __shfl_xor(tm, 4, 64));
      tm = fmaxf(tm, __shfl_xor(tm, 8, 64));
      float mnew = fmaxf(mrow[r], tm);
      float alpha = exp2f((mrow[r] - mnew) * LOG2E);
      mrow[r] = mnew;
      float rs = 0.f;
      #pragma unroll
      for (int ct = 0; ct < 4; ct++){
        float pv = exp2f((p_[ct][r] - mnew) * LOG2E);
        p_[ct][r] = pv; rs += pv;
      }
      rs += __shfl_xor(rs, 1, 64); rs += __shfl_xor(rs, 2, 64);
      rs += __shfl_xor(rs, 4, 64); rs += __shfl_xor(rs, 8, 64);
      lrow[r] = lrow[r] * alpha + rs;
      #pragma unroll
      for (int nt = 0; nt < 4; nt++) cacc[nt][r] *= alpha;
    }

    // P (C-layout) -> per-wave LDS -> A-layout fragments
    unsigned short* pw = &Ps[w][0];
    #pragma unroll
    for (int ct = 0; ct < 4; ct++)
      #pragma unroll
      for (int r = 0; r < 4; r++)
        pw[(q*4 + r)*72 + ct*16 + c] = f2bf(p_[ct][r]);

    s16x8 pf0 = *(const s16x8*)(pw + c*72 + q*8);
    s16x8 pf1 = *(const s16x8*)(pw + c*72 + 32 + q*8);
    #pragma unroll
    for (int nt = 0; nt < 4; nt++){
      int d = nt*16 + c;
      s16x8 vf0 = *(const s16x8*)(Vs + d*64 + ((0 + q) ^ (d & 7)) * 8);
      s16x8 vf1 = *(const s16x8*)(Vs + d*64 + ((4 + q) ^ (d & 7)) * 8);
      cacc[nt] = __builtin_amdgcn_mfma_f32_16x16x32_bf16(pf0, vf0, cacc[nt], 0, 0, 0);
      cacc[nt] = __builtin_amdgcn_mfma_f32_16x16x32_bf16(pf1, vf1, cacc[nt], 0, 0, 0);
    }
  }

  // epilogue: ctx = acc / l, bf16, [tok][h*64+d]
  float inv[4];
  #pragma unroll
  for (int r = 0; r < 4; r++) inv[r] = 1.0f / lrow[r];
  #pragma unroll
  for (int nt = 0; nt < 4; nt++){
    int d = nt*16 + c;
    #pragma unroll
    for (int r = 0; r < 4; r++){
      int ig = i0 + w*16 + q*4 + r;
      ctx[(size_t)(b*SS + ig) * HID + h*DHEAD + d] = f2bf(cacc[nt][r] * inv[r]);
    }
  }
}

// ---------------------------------------------------------------------------
// 5) out = ctx @ Wo + bo  (f32 out)
// ---------------------------------------------------------------------------
__global__ __launch_bounds__(256) void k_gemm_out(const unsigned short* __restrict__ A,
                                                  const unsigned short* __restrict__ Bt,
                                                  float* __restrict__ out,
                                                  const float* __restrict__ bo){
  __shared__ __align__(16) unsigned short As[128*32];
  __shared__ __align__(16) unsigned short Bs[128*32];
  int t = threadIdx.x;
  int L = t & 63, w = t >> 6;
  int q = L >> 4, c = L & 15;
  int m0 = blockIdx.x * 128, n0 = blockIdx.y * 128;
  int wr = w >> 1, wc = w & 1;
  f32x4 acc[4][4];
  #pragma unroll
  for (int i = 0; i < 4; i++)
    #pragma unroll
    for (int j = 0; j < 4; j++) acc[i][j] = (f32x4){0.f,0.f,0.f,0.f};

  for (int kb = 0; kb < 32; kb++){
    __syncthreads();
    #pragma unroll
    for (int i = 0; i < 2; i++){
      int p = t + i*256;
      int row = p >> 2, cp = p & 3;
      gl2lds16(A  + (m0 + row) * HID + kb*32 + cp*8, As + p*8);
      gl2lds16(Bt + (n0 + row) * HID + kb*32 + cp*8, Bs + p*8);
    }
    __syncthreads();
    s16x8 af[4], bf[4];
    #pragma unroll
    for (int i = 0; i < 4; i++){
      int m = wr*64 + i*16 + c;
      af[i] = *(const s16x8*)(As + m*32 + q*8);
      int n = wc*64 + i*16 + c;
      bf[i] = *(const s16x8*)(Bs + n*32 + q*8);
    }
    #pragma unroll
    for (int i = 0; i < 4; i++)
      #pragma unroll
      for (int j = 0; j < 4; j++)
        acc[i][j] = __builtin_amdgcn_mfma_f32_16x16x32_bf16(af[i], bf[j], acc[i][j], 0, 0, 0);
  }

  #pragma unroll
  for (int j = 0; j < 4; j++){
    int n = n0 + wc*64 + j*16 + c;
    float bv = bo[n];
    #pragma unroll
    for (int i = 0; i < 4; i++){
      int m = m0 + wr*64 + i*16 + q*4;
      #pragma unroll
      for (int r = 0; r < 4; r++)
        out[(size_t)(m + r) * HID + n] = acc[i][j][r] + bv;
    }
  }
}

// ---------------------------------------------------------------------------
extern "C" void kernel_launch(void* const* d_in, const int* in_sizes, int n_in,
                              void* d_out, int out_size, void* d_ws, size_t ws_size,
                              hipStream_t stream){
  const float* hs    = (const float*)d_in[0];
  const int*   amask = (const int*)  d_in[1];
  const float* Wq    = (const float*)d_in[2];
  const float* Wk    = (const float*)d_in[3];
  const float* Wv    = (const float*)d_in[4];
  const float* Wo    = (const float*)d_in[5];
  const float* bo    = (const float*)d_in[6];
  // d_in[7] = alibi: intentionally unused (computed analytically; saves 268 MB of reads)
  float* out = (float*)d_out;

  char* ws = (char*)d_ws;                                        // 48 MB used
  unsigned short* Xb  = (unsigned short*)(ws);                   //  8 MB  [4096][1024]
  unsigned short* Wt  = (unsigned short*)(ws + (8u  << 20));     //  6 MB  [3072][1024]
  unsigned short* Wot = (unsigned short*)(ws + (14u << 20));     //  2 MB  [1024][1024]
  unsigned short* Qb  = (unsigned short*)(ws + (16u << 20));     //  8 MB
  unsigned short* Kb  = (unsigned short*)(ws + (24u << 20));     //  8 MB
  unsigned short* Vt  = (unsigned short*)(ws + (32u << 20));     //  8 MB  [b][h][d][s]
  unsigned short* Ctx = (unsigned short*)(ws + (40u << 20));     //  8 MB

  hipLaunchKernelGGL(k_convert_x, dim3(MTOT*HID/4/256), dim3(256), 0, stream, hs, Xb);
  hipLaunchKernelGGL(k_convert_w, dim3(16,16,4), dim3(256), 0, stream, Wq, Wk, Wv, Wo, Wt, Wot);
  hipLaunchKernelGGL(k_gemm_qkv,  dim3(32,24),   dim3(256), 0, stream, Xb, Wt, Qb, Kb, Vt);
  hipLaunchKernelGGL(k_attn,      dim3(32,32),   dim3(256), 0, stream, Qb, Kb, Vt, amask, Ctx);
  hipLaunchKernelGGL(k_gemm_out,  dim3(32,8),    dim3(256), 0, stream, Ctx, Wot, out, bo);
}

// Round 2
// 555.498 us; speedup vs baseline: 1.1387x; 1.1387x over previous
//
#include <hip/hip_runtime.h>
#include <stdint.h>

// Shapes (fixed by the problem)
#define BB 2
#define SS 2048
#define HID 1024
#define NHEAD 16
#define DHEAD 64
#define MTOT (BB*SS)          // 4096 tokens

typedef float  f32x4  __attribute__((ext_vector_type(4)));
typedef short  s16x8  __attribute__((ext_vector_type(8)));
typedef unsigned short u16x4 __attribute__((ext_vector_type(4)));

#define LOG2E 1.4426950408889634f

// round-to-nearest-even f32 -> bf16 (bit pattern)
__device__ __forceinline__ unsigned short f2bf(float x){
  union { float f; unsigned u; } v; v.f = x;
  unsigned r = v.u + 0x7fffu + ((v.u >> 16) & 1u);
  return (unsigned short)(r >> 16);
}

// async global->LDS, 16 bytes per lane (dest must be wave-uniform base + lane*16)
__device__ __forceinline__ void gl2lds16(const unsigned short* g, unsigned short* l){
  __builtin_amdgcn_global_load_lds((const __attribute__((address_space(1))) void*)g,
                                   (__attribute__((address_space(3))) void*)l, 16, 0, 0);
}

// ---------------------------------------------------------------------------
// 1) hidden_states f32 -> bf16 (row-major [4096][1024])
// ---------------------------------------------------------------------------
__global__ __launch_bounds__(256) void k_convert_x(const float* __restrict__ x,
                                                   unsigned short* __restrict__ xb){
  int i = blockIdx.x * 256 + threadIdx.x;   // one float4 per thread
  const float4* xp = (const float4*)x;
  float4 v = xp[i];
  u16x4 o; o.x = f2bf(v.x); o.y = f2bf(v.y); o.z = f2bf(v.z); o.w = f2bf(v.w);
  ((u16x4*)xb)[i] = o;
}

// ---------------------------------------------------------------------------
// 2) weights f32 [K][N] -> bf16 transposed [N][K] (Wq,Wk,Wv -> Wt rows 0..3071; Wo -> Wot)
// ---------------------------------------------------------------------------
__global__ __launch_bounds__(256) void k_convert_w(const float* __restrict__ Wq,
                                                   const float* __restrict__ Wk,
                                                   const float* __restrict__ Wv,
                                                   const float* __restrict__ Wo,
                                                   unsigned short* __restrict__ Wt,
                                                   unsigned short* __restrict__ Wot){
  __shared__ float tile[64][65];
  int z = blockIdx.z;
  const float* src = (z==0) ? Wq : (z==1) ? Wk : (z==2) ? Wv : Wo;
  unsigned short* dst = (z < 3) ? (Wt + z * HID * HID) : Wot;
  int n0 = blockIdx.x * 64, k0 = blockIdx.y * 64;
  int t = threadIdx.x, tx = t & 63, ty = t >> 6;
  #pragma unroll
  for (int i = 0; i < 16; i++){
    int kl = ty + i*4;
    tile[kl][tx] = src[(k0 + kl) * HID + n0 + tx];
  }
  __syncthreads();
  #pragma unroll
  for (int i = 0; i < 16; i++){
    int nl = ty + i*4;
    dst[(n0 + nl) * HID + k0 + tx] = f2bf(tile[tx][nl]);
  }
}

// ---------------------------------------------------------------------------
// 3) QKV GEMM: Xb[4096][1024] @ Wt[3072][1024]^T -> Qb (x0.125), Kb, Vt (transposed per head)
//    m97 structure: 128x128 tile, BK=32, 4 waves in 2x2, 16 MFMA/wave/k-step
// ---------------------------------------------------------------------------
__global__ __launch_bounds__(256) void k_gemm_qkv(const unsigned short* __restrict__ A,
                                                  const unsigned short* __restrict__ Bt,
                                                  unsigned short* __restrict__ Qb,
                                                  unsigned short* __restrict__ Kb,
                                                  unsigned short* __restrict__ Vt){
  __shared__ __align__(16) unsigned short As[128*32];
  __shared__ __align__(16) unsigned short Bs[128*32];
  int t = threadIdx.x;
  int L = t & 63, w = t >> 6;
  int q = L >> 4, c = L & 15;
  int m0 = blockIdx.x * 128, n0 = blockIdx.y * 128;
  int wr = w >> 1, wc = w & 1;
  f32x4 acc[4][4];
  #pragma unroll
  for (int i = 0; i < 4; i++)
    #pragma unroll
    for (int j = 0; j < 4; j++) acc[i][j] = (f32x4){0.f,0.f,0.f,0.f};

  for (int kb = 0; kb < 32; kb++){
    __syncthreads();
    #pragma unroll
    for (int i = 0; i < 2; i++){
      int p = t + i*256;                // 512 chunks of 16B per tile
      int row = p >> 2, cp = p & 3;     // [128 rows][4 chunks]
      gl2lds16(A  + (m0 + row) * HID + kb*32 + cp*8, As + p*8);
      gl2lds16(Bt + (n0 + row) * HID + kb*32 + cp*8, Bs + p*8);
    }
    __syncthreads();
    s16x8 af[4], bf[4];
    #pragma unroll
    for (int i = 0; i < 4; i++){
      int m = wr*64 + i*16 + c;
      af[i] = *(const s16x8*)(As + m*32 + q*8);
      int n = wc*64 + i*16 + c;
      bf[i] = *(const s16x8*)(Bs + n*32 + q*8);
    }
    #pragma unroll
    for (int i = 0; i < 4; i++)
      #pragma unroll
      for (int j = 0; j < 4; j++)
        acc[i][j] = __builtin_amdgcn_mfma_f32_16x16x32_bf16(af[i], bf[j], acc[i][j], 0, 0, 0);
  }

  int wsel = n0 >> 10;                  // 0=Q, 1=K, 2=V (128 | 1024, never straddles)
  #pragma unroll
  for (int i = 0; i < 4; i++){
    #pragma unroll
    for (int j = 0; j < 4; j++){
      int m_l = wr*64 + i*16 + q*4;
      int n_g = n0 + wc*64 + j*16 + c;
      int nw  = n_g & 1023;
      if (wsel == 0){
        #pragma unroll
        for (int r = 0; r < 4; r++)
          Qb[(m0 + m_l + r) * HID + nw] = f2bf(acc[i][j][r] * 0.125f);  // fold 1/sqrt(64)
      } else if (wsel == 1){
        #pragma unroll
        for (int r = 0; r < 4; r++)
          Kb[(m0 + m_l + r) * HID + nw] = f2bf(acc[i][j][r]);
      } else {
        int tok = m0 + m_l;
        int b = tok >> 11, s = tok & 2047;
        int h = nw >> 6, d = nw & 63;
        u16x4 pk;
        pk.x = f2bf(acc[i][j][0]); pk.y = f2bf(acc[i][j][1]);
        pk.z = f2bf(acc[i][j][2]); pk.w = f2bf(acc[i][j][3]);
        *(u16x4*)(Vt + (((b*NHEAD + h)*DHEAD + d) * (size_t)SS + s)) = pk; // Vt[b][h][d][s]
      }
    }
  }
}

// ---------------------------------------------------------------------------
// 4) Flash attention, FIXED-MAX softmax.
//    After the 30*tanh(s/30) softcap, scores are in [-30,30], so shift by the
//    constant 30 instead of a running max:  p = exp(cap(s) - 30)
//      log2 p = -86.5617 / (exp2(0.0961797*s) + 1)      (exact algebra)
//    -> no running max, no alpha rescale, no per-tile cross-lane shuffles;
//    l is a per-lane partial sum reduced once at the end.
//    LDS: P-transpose buffer unioned into the (dead-after-prologue) Q tile:
//    25.6 KB/block -> 6 blocks/CU (was 33.8 KB -> 4).
// ---------------------------------------------------------------------------
__global__ __launch_bounds__(256) void k_attn(const unsigned short* __restrict__ Qb,
                                              const unsigned short* __restrict__ Kb,
                                              const unsigned short* __restrict__ Vt,
                                              const int* __restrict__ amask,
                                              unsigned short* __restrict__ ctx){
  // union region: first 64*64 shorts = Q staging tile; later reused as
  // per-wave P tiles [4][16 rows][stride 72]
  __shared__ __align__(16) unsigned short UQ[4*16*72];   // 9216 B
  __shared__ __align__(16) unsigned short Ks[64*64];
  __shared__ __align__(16) unsigned short Vs[64*64];

  int t = threadIdx.x;
  int L = t & 63, w = t >> 6;
  int q = L >> 4, c = L & 15;
  int qt = 31 - (int)blockIdx.x;        // big (late) q-tiles first -> better tail
  int bh = blockIdx.y;
  int b = bh >> 4, h = bh & 15;
  int i0 = qt * 64;

  // ALiBi slope * 0.125 (exact): slope = 2^{-(h+1)/2}, /8 folded in
  int hp = h + 1;
  float slope = (hp & 1) ? 0.70710678118654752f : 1.0f;
  slope = ldexpf(slope, -((hp >> 1) + 3));

  // stage Q tile [64 rows][64 d], XOR chunk swizzle (chunk ^= row&7)
  #pragma unroll
  for (int i = 0; i < 2; i++){
    int p = t + i*256; int row = p >> 3, cp = p & 7; int gc = cp ^ (row & 7);
    gl2lds16(Qb + (size_t)(b*SS + i0 + row) * HID + h*DHEAD + gc*8, UQ + p*8);
  }
  __syncthreads();
  s16x8 qf0, qf1;
  {
    int m = w*16 + c;
    qf0 = *(const s16x8*)(UQ + m*64 + ((0 + q) ^ (m & 7)) * 8);
    qf1 = *(const s16x8*)(UQ + m*64 + ((4 + q) ^ (m & 7)) * 8);
  }

  f32x4 cacc[4];
  #pragma unroll
  for (int i = 0; i < 4; i++) cacc[i] = (f32x4){0.f,0.f,0.f,0.f};
  float lrow[4] = {0.f,0.f,0.f,0.f};

  const float C1 = 86.5617024533378f;     // 60*log2(e)
  const float C2 = 0.0961796693925976f;   // 2*log2(e)/30

  for (int jt = 0; jt <= qt; jt++){
    int j0 = jt * 64;
    __syncthreads();                 // all waves done reading last K/V/P tiles
    #pragma unroll
    for (int i = 0; i < 2; i++){
      int p = t + i*256; int row = p >> 3, cp = p & 7; int gc = cp ^ (row & 7);
      gl2lds16(Kb + (size_t)(b*SS + j0 + row) * HID + h*DHEAD + gc*8, Ks + p*8);
      gl2lds16(Vt + (size_t)(bh*DHEAD + row) * SS + j0 + gc*8, Vs + p*8);
    }
    __syncthreads();

    // S = Q K^T  (rows: this wave's 16; cols: 64)
    f32x4 sacc[4];
    #pragma unroll
    for (int ct = 0; ct < 4; ct++){
      int n = ct*16 + c;
      s16x8 kf0 = *(const s16x8*)(Ks + n*64 + ((0 + q) ^ (n & 7)) * 8);
      s16x8 kf1 = *(const s16x8*)(Ks + n*64 + ((4 + q) ^ (n & 7)) * 8);
      f32x4 z = (f32x4){0.f,0.f,0.f,0.f};
      z = __builtin_amdgcn_mfma_f32_16x16x32_bf16(qf0, kf0, z, 0, 0, 0);
      z = __builtin_amdgcn_mfma_f32_16x16x32_bf16(qf1, kf1, z, 0, 0, 0);
      sacc[ct] = z;
    }

    // p = exp(cap(s)-30), causal+pad masked; accumulate per-lane l partials
    float p_[4][4];
    #pragma unroll
    for (int ct = 0; ct < 4; ct++){
      int jg = j0 + ct*16 + c;
      int pad = amask[b*SS + jg];
      #pragma unroll
      for (int r = 0; r < 4; r++){
        int ig = i0 + w*16 + q*4 + r;
        float s = sacc[ct][r] + slope * (float)(jg - ig);
        float e2 = exp2f(s * C2);
        float pv = exp2f(-C1 / (e2 + 1.0f));
        bool ok = (jg <= ig) && (pad != 0);
        pv = ok ? pv : 0.0f;
        p_[ct][r] = pv;
        lrow[r] += pv;
      }
    }

    // P (C-layout) -> per-wave LDS -> A-layout fragments
    unsigned short* pw = UQ + w * (16*72);
    #pragma unroll
    for (int ct = 0; ct < 4; ct++)
      #pragma unroll
      for (int r = 0; r < 4; r++)
        pw[(q*4 + r)*72 + ct*16 + c] = f2bf(p_[ct][r]);

    s16x8 pf0 = *(const s16x8*)(pw + c*72 + q*8);
    s16x8 pf1 = *(const s16x8*)(pw + c*72 + 32 + q*8);
    #pragma unroll
    for (int nt = 0; nt < 4; nt++){
      int d = nt*16 + c;
      s16x8 vf0 = *(const s16x8*)(Vs + d*64 + ((0 + q) ^ (d & 7)) * 8);
      s16x8 vf1 = *(const s16x8*)(Vs + d*64 + ((4 + q) ^ (d & 7)) * 8);
      cacc[nt] = __builtin_amdgcn_mfma_f32_16x16x32_bf16(pf0, vf0, cacc[nt], 0, 0, 0);
      cacc[nt] = __builtin_amdgcn_mfma_f32_16x16x32_bf16(pf1, vf1, cacc[nt], 0, 0, 0);
    }
  }

  // final l reduction across the 16 c-lanes of each quad, then epilogue
  float inv[4];
  #pragma unroll
  for (int r = 0; r < 4; r++){
    float l = lrow[r];
    l += __shfl_xor(l, 1, 64);
    l += __shfl_xor(l, 2, 64);
    l += __shfl_xor(l, 4, 64);
    l += __shfl_xor(l, 8, 64);
    inv[r] = 1.0f / l;
  }
  #pragma unroll
  for (int nt = 0; nt < 4; nt++){
    int d = nt*16 + c;
    #pragma unroll
    for (int r = 0; r < 4; r++){
      int ig = i0 + w*16 + q*4 + r;
      ctx[(size_t)(b*SS + ig) * HID + h*DHEAD + d] = f2bf(cacc[nt][r] * inv[r]);
    }
  }
}

// ---------------------------------------------------------------------------
// 5) out = ctx @ Wo + bo  (f32 out)
// ---------------------------------------------------------------------------
__global__ __launch_bounds__(256) void k_gemm_out(const unsigned short* __restrict__ A,
                                                  const unsigned short* __restrict__ Bt,
                                                  float* __restrict__ out,
                                                  const float* __restrict__ bo){
  __shared__ __align__(16) unsigned short As[128*32];
  __shared__ __align__(16) unsigned short Bs[128*32];
  int t = threadIdx.x;
  int L = t & 63, w = t >> 6;
  int q = L >> 4, c = L & 15;
  int m0 = blockIdx.x * 128, n0 = blockIdx.y * 128;
  int wr = w >> 1, wc = w & 1;
  f32x4 acc[4][4];
  #pragma unroll
  for (int i = 0; i < 4; i++)
    #pragma unroll
    for (int j = 0; j < 4; j++) acc[i][j] = (f32x4){0.f,0.f,0.f,0.f};

  for (int kb = 0; kb < 32; kb++){
    __syncthreads();
    #pragma unroll
    for (int i = 0; i < 2; i++){
      int p = t + i*256;
      int row = p >> 2, cp = p & 3;
      gl2lds16(A  + (m0 + row) * HID + kb*32 + cp*8, As + p*8);
      gl2lds16(Bt + (n0 + row) * HID + kb*32 + cp*8, Bs + p*8);
    }
    __syncthreads();
    s16x8 af[4], bf[4];
    #pragma unroll
    for (int i = 0; i < 4; i++){
      int m = wr*64 + i*16 + c;
      af[i] = *(const s16x8*)(As + m*32 + q*8);
      int n = wc*64 + i*16 + c;
      bf[i] = *(const s16x8*)(Bs + n*32 + q*8);
    }
    #pragma unroll
    for (int i = 0; i < 4; i++)
      #pragma unroll
      for (int j = 0; j < 4; j++)
        acc[i][j] = __builtin_amdgcn_mfma_f32_16x16x32_bf16(af[i], bf[j], acc[i][j], 0, 0, 0);
  }

  #pragma unroll
  for (int j = 0; j < 4; j++){
    int n = n0 + wc*64 + j*16 + c;
    float bv = bo[n];
    #pragma unroll
    for (int i = 0; i < 4; i++){
      int m = m0 + wr*64 + i*16 + q*4;
      #pragma unroll
      for (int r = 0; r < 4; r++)
        out[(size_t)(m + r) * HID + n] = acc[i][j][r] + bv;
    }
  }
}

// ---------------------------------------------------------------------------
extern "C" void kernel_launch(void* const* d_in, const int* in_sizes, int n_in,
                              void* d_out, int out_size, void* d_ws, size_t ws_size,
                              hipStream_t stream){
  const float* hs    = (const float*)d_in[0];
  const int*   amask = (const int*)  d_in[1];
  const float* Wq    = (const float*)d_in[2];
  const float* Wk    = (const float*)d_in[3];
  const float* Wv    = (const float*)d_in[4];
  const float* Wo    = (const float*)d_in[5];
  const float* bo    = (const float*)d_in[6];
  // d_in[7] = alibi: intentionally unused (computed analytically; saves 268 MB of reads)
  float* out = (float*)d_out;

  char* ws = (char*)d_ws;                                        // 48 MB used
  unsigned short* Xb  = (unsigned short*)(ws);                   //  8 MB  [4096][1024]
  unsigned short* Wt  = (unsigned short*)(ws + (8u  << 20));     //  6 MB  [3072][1024]
  unsigned short* Wot = (unsigned short*)(ws + (14u << 20));     //  2 MB  [1024][1024]
  unsigned short* Qb  = (unsigned short*)(ws + (16u << 20));     //  8 MB
  unsigned short* Kb  = (unsigned short*)(ws + (24u << 20));     //  8 MB
  unsigned short* Vt  = (unsigned short*)(ws + (32u << 20));     //  8 MB  [b][h][d][s]
  unsigned short* Ctx = (unsigned short*)(ws + (40u << 20));     //  8 MB

  hipLaunchKernelGGL(k_convert_x, dim3(MTOT*HID/4/256), dim3(256), 0, stream, hs, Xb);
  hipLaunchKernelGGL(k_convert_w, dim3(16,16,4), dim3(256), 0, stream, Wq, Wk, Wv, Wo, Wt, Wot);
  hipLaunchKernelGGL(k_gemm_qkv,  dim3(32,24),   dim3(256), 0, stream, Xb, Wt, Qb, Kb, Vt);
  hipLaunchKernelGGL(k_attn,      dim3(32,32),   dim3(256), 0, stream, Qb, Kb, Vt, amask, Ctx);
  hipLaunchKernelGGL(k_gemm_out,  dim3(32,8),    dim3(256), 0, stream, Ctx, Wot, out, bo);
}

// Round 3
// 471.941 us; speedup vs baseline: 1.3403x; 1.1771x over previous
//
#include <hip/hip_runtime.h>
#include <stdint.h>

// Shapes (fixed by the problem)
#define BB 2
#define SS 2048
#define HID 1024
#define NHEAD 16
#define DHEAD 64
#define MTOT (BB*SS)          // 4096 tokens

typedef float  f32x4  __attribute__((ext_vector_type(4)));
typedef short  s16x8  __attribute__((ext_vector_type(8)));
typedef unsigned short u16x4 __attribute__((ext_vector_type(4)));

#define LOG2E 1.4426950408889634f

// round-to-nearest-even f32 -> bf16 (bit pattern)
__device__ __forceinline__ unsigned short f2bf(float x){
  union { float f; unsigned u; } v; v.f = x;
  unsigned r = v.u + 0x7fffu + ((v.u >> 16) & 1u);
  return (unsigned short)(r >> 16);
}
__device__ __forceinline__ float bf2f(unsigned short h){
  union { unsigned u; float f; } v; v.u = ((unsigned)h) << 16; return v.f;
}

// async global->LDS, 16 bytes per lane (dest must be wave-uniform base + lane*16)
__device__ __forceinline__ void gl2lds16(const unsigned short* g, unsigned short* l){
  __builtin_amdgcn_global_load_lds((const __attribute__((address_space(1))) void*)g,
                                   (__attribute__((address_space(3))) void*)l, 16, 0, 0);
}

// ---------------------------------------------------------------------------
// 1) hidden_states f32 -> bf16 (row-major [4096][1024])
// ---------------------------------------------------------------------------
__global__ __launch_bounds__(256) void k_convert_x(const float* __restrict__ x,
                                                   unsigned short* __restrict__ xb){
  int i = blockIdx.x * 256 + threadIdx.x;   // one float4 per thread
  const float4* xp = (const float4*)x;
  float4 v = xp[i];
  u16x4 o; o.x = f2bf(v.x); o.y = f2bf(v.y); o.z = f2bf(v.z); o.w = f2bf(v.w);
  ((u16x4*)xb)[i] = o;
}

// ---------------------------------------------------------------------------
// 2) weights f32 [K][N] -> bf16 transposed [N][K] (Wq,Wk,Wv -> Wt rows 0..3071; Wo -> Wot)
// ---------------------------------------------------------------------------
__global__ __launch_bounds__(256) void k_convert_w(const float* __restrict__ Wq,
                                                   const float* __restrict__ Wk,
                                                   const float* __restrict__ Wv,
                                                   const float* __restrict__ Wo,
                                                   unsigned short* __restrict__ Wt,
                                                   unsigned short* __restrict__ Wot){
  __shared__ float tile[64][65];
  int z = blockIdx.z;
  const float* src = (z==0) ? Wq : (z==1) ? Wk : (z==2) ? Wv : Wo;
  unsigned short* dst = (z < 3) ? (Wt + z * HID * HID) : Wot;
  int n0 = blockIdx.x * 64, k0 = blockIdx.y * 64;
  int t = threadIdx.x, tx = t & 63, ty = t >> 6;
  #pragma unroll
  for (int i = 0; i < 16; i++){
    int kl = ty + i*4;
    tile[kl][tx] = src[(k0 + kl) * HID + n0 + tx];
  }
  __syncthreads();
  #pragma unroll
  for (int i = 0; i < 16; i++){
    int nl = ty + i*4;
    dst[(n0 + nl) * HID + k0 + tx] = f2bf(tile[tx][nl]);
  }
}

// ---------------------------------------------------------------------------
// 3) QKV GEMM: Xb[4096][1024] @ Wt[3072][1024]^T -> Qb (x0.125), Kb, Vb
//    all three outputs in [token][hd] row-major (coalesced epilogue);
//    V gets transposed to [b][h][d][s] by k_transpose_v afterwards.
// ---------------------------------------------------------------------------
__global__ __launch_bounds__(256) void k_gemm_qkv(const unsigned short* __restrict__ A,
                                                  const unsigned short* __restrict__ Bt,
                                                  unsigned short* __restrict__ Qb,
                                                  unsigned short* __restrict__ Kb,
                                                  unsigned short* __restrict__ Vb){
  __shared__ __align__(16) unsigned short As[128*32];
  __shared__ __align__(16) unsigned short Bs[128*32];
  int t = threadIdx.x;
  int L = t & 63, w = t >> 6;
  int q = L >> 4, c = L & 15;
  int m0 = blockIdx.x * 128, n0 = blockIdx.y * 128;
  int wr = w >> 1, wc = w & 1;
  f32x4 acc[4][4];
  #pragma unroll
  for (int i = 0; i < 4; i++)
    #pragma unroll
    for (int j = 0; j < 4; j++) acc[i][j] = (f32x4){0.f,0.f,0.f,0.f};

  for (int kb = 0; kb < 32; kb++){
    __syncthreads();
    #pragma unroll
    for (int i = 0; i < 2; i++){
      int p = t + i*256;                // 512 chunks of 16B per tile
      int row = p >> 2, cp = p & 3;     // [128 rows][4 chunks]
      gl2lds16(A  + (m0 + row) * HID + kb*32 + cp*8, As + p*8);
      gl2lds16(Bt + (n0 + row) * HID + kb*32 + cp*8, Bs + p*8);
    }
    __syncthreads();
    s16x8 af[4], bf[4];
    #pragma unroll
    for (int i = 0; i < 4; i++){
      int m = wr*64 + i*16 + c;
      af[i] = *(const s16x8*)(As + m*32 + q*8);
      int n = wc*64 + i*16 + c;
      bf[i] = *(const s16x8*)(Bs + n*32 + q*8);
    }
    #pragma unroll
    for (int i = 0; i < 4; i++)
      #pragma unroll
      for (int j = 0; j < 4; j++)
        acc[i][j] = __builtin_amdgcn_mfma_f32_16x16x32_bf16(af[i], bf[j], acc[i][j], 0, 0, 0);
  }

  int wsel = n0 >> 10;                  // 0=Q, 1=K, 2=V (128 | 1024, never straddles)
  unsigned short* dst = (wsel==0) ? Qb : (wsel==1) ? Kb : Vb;
  float scale = (wsel==0) ? 0.125f : 1.0f;   // fold 1/sqrt(64) into Q
  #pragma unroll
  for (int i = 0; i < 4; i++){
    #pragma unroll
    for (int j = 0; j < 4; j++){
      int m_l = wr*64 + i*16 + q*4;
      int nw  = (n0 + wc*64 + j*16 + c) & 1023;
      #pragma unroll
      for (int r = 0; r < 4; r++)
        dst[(m0 + m_l + r) * HID + nw] = f2bf(acc[i][j][r] * scale);
    }
  }
}

// ---------------------------------------------------------------------------
// 3b) V transpose: Vb [tok][h*64+d] -> Vt [b][h][d][s]  (LDS 64x64 tile)
//     u32-packed LDS (2 d-values per word), pad to 33 words.
// ---------------------------------------------------------------------------
__global__ __launch_bounds__(256) void k_transpose_v(const unsigned short* __restrict__ Vb,
                                                     unsigned short* __restrict__ Vt){
  __shared__ unsigned tile[64][33];
  int st = blockIdx.x, bh = blockIdx.y;
  int b = bh >> 4, h = bh & 15;
  int t = threadIdx.x;
  int lr = t >> 4, lc = t & 15;
  #pragma unroll
  for (int i = 0; i < 4; i++){
    int sl = lr + i*16;
    u16x4 v = *(const u16x4*)(Vb + (size_t)(b*SS + st*64 + sl) * HID + h*DHEAD + lc*4);
    tile[sl][lc*2]     = (unsigned)v.x | ((unsigned)v.y << 16);
    tile[sl][lc*2 + 1] = (unsigned)v.z | ((unsigned)v.w << 16);
  }
  __syncthreads();
  #pragma unroll
  for (int i = 0; i < 4; i++){
    int dl = lr + i*16;
    int sh = (dl & 1) * 16, dw = dl >> 1;
    u16x4 o;
    o.x = (unsigned short)(tile[lc*4 + 0][dw] >> sh);
    o.y = (unsigned short)(tile[lc*4 + 1][dw] >> sh);
    o.z = (unsigned short)(tile[lc*4 + 2][dw] >> sh);
    o.w = (unsigned short)(tile[lc*4 + 3][dw] >> sh);
    *(u16x4*)(Vt + (size_t)(bh*DHEAD + dl) * SS + st*64 + lc*4) = o;
  }
}

// ---------------------------------------------------------------------------
// 4) Flash attention, FIXED-MAX softmax, j-SPLIT for load balance.
//    p = exp(30*tanh(s/30) - 30): fixed shift -> partials over any j-range are
//    PLAIN SUMS (no rescale). qt>=16 items split into 2 j-chunks:
//      chunk0 -> unnormalized bf16 numerator NumBf + f32 Lsum (single writer)
//      chunk1 -> f32 partials Part2/L2 in scratch
//    k_combine adds + normalizes. Grid 48x32 = 1536 blocks = 6/CU, fully
//    resident; max item 16 j-tiles (was 32).
// ---------------------------------------------------------------------------
__global__ __launch_bounds__(256) void k_attn(const unsigned short* __restrict__ Qb,
                                              const unsigned short* __restrict__ Kb,
                                              const unsigned short* __restrict__ Vt,
                                              const int* __restrict__ amask,
                                              unsigned short* __restrict__ NumBf,
                                              float* __restrict__ Lsum,
                                              float* __restrict__ Part2,
                                              float* __restrict__ L2){
  // union region: first 64*64 shorts = Q staging tile; later per-wave P tiles
  __shared__ __align__(16) unsigned short UQ[4*16*72];   // 9216 B
  __shared__ __align__(16) unsigned short Ks[64*64];
  __shared__ __align__(16) unsigned short Vs[64*64];

  int t = threadIdx.x;
  int L = t & 63, w = t >> 6;
  int q = L >> 4, c = L & 15;
  int x = blockIdx.x;                  // dispatch order: longest chunks first
  int bh = blockIdx.y;
  int b = bh >> 4, h = bh & 15;

  int qt, jt0, jt1, chunk1;
  if (x < 32){
    qt = 31 - (x >> 1);                // qt in [16,31]
    int h0 = (qt + 1) >> 1;
    chunk1 = x & 1;
    jt0 = chunk1 ? h0 : 0;
    jt1 = chunk1 ? (qt + 1) : h0;
  } else {
    qt = 47 - x;                       // qt in [0,15]
    jt0 = 0; jt1 = qt + 1; chunk1 = 0;
  }
  int i0 = qt * 64;

  // ALiBi slope * 0.125 (exact): slope = 2^{-(h+1)/2}, /8 folded in
  int hp = h + 1;
  float slope = (hp & 1) ? 0.70710678118654752f : 1.0f;
  slope = ldexpf(slope, -((hp >> 1) + 3));

  // stage Q tile [64 rows][64 d], XOR chunk swizzle (chunk ^= row&7)
  #pragma unroll
  for (int i = 0; i < 2; i++){
    int p = t + i*256; int row = p >> 3, cp = p & 7; int gc = cp ^ (row & 7);
    gl2lds16(Qb + (size_t)(b*SS + i0 + row) * HID + h*DHEAD + gc*8, UQ + p*8);
  }
  __syncthreads();
  s16x8 qf0, qf1;
  {
    int m = w*16 + c;
    qf0 = *(const s16x8*)(UQ + m*64 + ((0 + q) ^ (m & 7)) * 8);
    qf1 = *(const s16x8*)(UQ + m*64 + ((4 + q) ^ (m & 7)) * 8);
  }

  // hoisted ALiBi row terms
  float si[4];
  #pragma unroll
  for (int r = 0; r < 4; r++) si[r] = slope * (float)(i0 + w*16 + q*4 + r);

  f32x4 cacc[4];
  #pragma unroll
  for (int i = 0; i < 4; i++) cacc[i] = (f32x4){0.f,0.f,0.f,0.f};
  float lrow[4] = {0.f,0.f,0.f,0.f};

  const float C1 = 86.5617024533378f;     // 60*log2(e)
  const float C2 = 0.0961796693925976f;   // 2*log2(e)/30

  for (int jt = jt0; jt < jt1; jt++){
    int j0 = jt * 64;
    __syncthreads();                 // all waves done reading last K/V/P tiles
    #pragma unroll
    for (int i = 0; i < 2; i++){
      int p = t + i*256; int row = p >> 3, cp = p & 7; int gc = cp ^ (row & 7);
      gl2lds16(Kb + (size_t)(b*SS + j0 + row) * HID + h*DHEAD + gc*8, Ks + p*8);
      gl2lds16(Vt + (size_t)(bh*DHEAD + row) * SS + j0 + gc*8, Vs + p*8);
    }
    __syncthreads();

    // S = Q K^T  (rows: this wave's 16; cols: 64)
    f32x4 sacc[4];
    #pragma unroll
    for (int ct = 0; ct < 4; ct++){
      int n = ct*16 + c;
      s16x8 kf0 = *(const s16x8*)(Ks + n*64 + ((0 + q) ^ (n & 7)) * 8);
      s16x8 kf1 = *(const s16x8*)(Ks + n*64 + ((4 + q) ^ (n & 7)) * 8);
      f32x4 z = (f32x4){0.f,0.f,0.f,0.f};
      z = __builtin_amdgcn_mfma_f32_16x16x32_bf16(qf0, kf0, z, 0, 0, 0);
      z = __builtin_amdgcn_mfma_f32_16x16x32_bf16(qf1, kf1, z, 0, 0, 0);
      sacc[ct] = z;
    }

    // p = exp(cap(s)-30): 2 exp2 + 1 rcp per score (fast rcp, err <= ~1e-4 in exponent)
    float p_[4][4];
    #pragma unroll
    for (int ct = 0; ct < 4; ct++){
      int jg = j0 + ct*16 + c;
      float padf = (amask[b*SS + jg] != 0) ? 1.0f : 0.0f;
      float sjg = slope * (float)jg;
      #pragma unroll
      for (int r = 0; r < 4; r++){
        float s = sacc[ct][r] + (sjg - si[r]);
        float e2 = exp2f(s * C2);
        float pv = exp2f(-C1 * __builtin_amdgcn_rcpf(e2 + 1.0f));
        p_[ct][r] = pv * padf;
      }
    }
    if (jt == qt){                    // causal mask: wave-uniform diagonal branch
      #pragma unroll
      for (int ct = 0; ct < 4; ct++){
        int jg = j0 + ct*16 + c;
        #pragma unroll
        for (int r = 0; r < 4; r++){
          int ig = i0 + w*16 + q*4 + r;
          if (jg > ig) p_[ct][r] = 0.0f;
        }
      }
    }
    #pragma unroll
    for (int ct = 0; ct < 4; ct++)
      #pragma unroll
      for (int r = 0; r < 4; r++) lrow[r] += p_[ct][r];

    // P (C-layout) -> per-wave LDS -> A-layout fragments
    unsigned short* pw = UQ + w * (16*72);
    #pragma unroll
    for (int ct = 0; ct < 4; ct++)
      #pragma unroll
      for (int r = 0; r < 4; r++)
        pw[(q*4 + r)*72 + ct*16 + c] = f2bf(p_[ct][r]);

    s16x8 pf0 = *(const s16x8*)(pw + c*72 + q*8);
    s16x8 pf1 = *(const s16x8*)(pw + c*72 + 32 + q*8);
    #pragma unroll
    for (int nt = 0; nt < 4; nt++){
      int d = nt*16 + c;
      s16x8 vf0 = *(const s16x8*)(Vs + d*64 + ((0 + q) ^ (d & 7)) * 8);
      s16x8 vf1 = *(const s16x8*)(Vs + d*64 + ((4 + q) ^ (d & 7)) * 8);
      cacc[nt] = __builtin_amdgcn_mfma_f32_16x16x32_bf16(pf0, vf0, cacc[nt], 0, 0, 0);
      cacc[nt] = __builtin_amdgcn_mfma_f32_16x16x32_bf16(pf1, vf1, cacc[nt], 0, 0, 0);
    }
  }

  // reduce l across the 16 c-lanes of each quad
  float lred[4];
  #pragma unroll
  for (int r = 0; r < 4; r++){
    float l = lrow[r];
    l += __shfl_xor(l, 1, 64);
    l += __shfl_xor(l, 2, 64);
    l += __shfl_xor(l, 4, 64);
    l += __shfl_xor(l, 8, 64);
    lred[r] = l;
  }

  if (!chunk1){
    // unnormalized bf16 numerator + f32 L (single writer per row)
    #pragma unroll
    for (int nt = 0; nt < 4; nt++){
      int d = nt*16 + c;
      #pragma unroll
      for (int r = 0; r < 4; r++){
        int ig = i0 + w*16 + q*4 + r;
        NumBf[(size_t)(b*SS + ig) * HID + h*DHEAD + d] = f2bf(cacc[nt][r]);
      }
    }
    if (c == 0){
      #pragma unroll
      for (int r = 0; r < 4; r++)
        Lsum[bh*SS + i0 + w*16 + q*4 + r] = lred[r];
    }
  } else {
    int slot = bh*16 + (qt - 16);
    float* pn = Part2 + (size_t)slot * 64 * 64;
    #pragma unroll
    for (int nt = 0; nt < 4; nt++){
      int d = nt*16 + c;
      #pragma unroll
      for (int r = 0; r < 4; r++){
        int row = w*16 + q*4 + r;
        pn[row*64 + d] = cacc[nt][r];
      }
    }
    if (c == 0){
      #pragma unroll
      for (int r = 0; r < 4; r++)
        L2[slot*64 + w*16 + q*4 + r] = lred[r];
    }
  }
}

// ---------------------------------------------------------------------------
// 4b) combine: ctx = (NumBf [+ Part2]) / (Lsum [+ L2]), bf16, in place on NumBf
// ---------------------------------------------------------------------------
__global__ __launch_bounds__(256) void k_combine(unsigned short* __restrict__ NumBf,
                                                 const float* __restrict__ Lsum,
                                                 const float* __restrict__ Part2,
                                                 const float* __restrict__ L2){
  int idx = blockIdx.x * 256 + threadIdx.x;    // one u16x4 (4 d-values)
  int tok = idx >> 8;
  int hd4 = (idx & 255) * 4;
  int h = hd4 >> 6, d0 = hd4 & 63;
  int b = tok >> 11, i = tok & 2047;
  int bh = b*16 + h, qt = i >> 6;
  u16x4 nv = *(u16x4*)(NumBf + (size_t)tok * HID + hd4);
  float n0 = bf2f(nv.x), n1 = bf2f(nv.y), n2 = bf2f(nv.z), n3 = bf2f(nv.w);
  float l = Lsum[bh*SS + i];
  if (qt >= 16){
    int slot = bh*16 + (qt - 16);
    const float* pn = Part2 + ((size_t)slot * 64 + (i & 63)) * 64 + d0;
    n0 += pn[0]; n1 += pn[1]; n2 += pn[2]; n3 += pn[3];
    l += L2[slot*64 + (i & 63)];
  }
  float rl = __builtin_amdgcn_rcpf(l);
  u16x4 o;
  o.x = f2bf(n0*rl); o.y = f2bf(n1*rl); o.z = f2bf(n2*rl); o.w = f2bf(n3*rl);
  *(u16x4*)(NumBf + (size_t)tok * HID + hd4) = o;
}

// ---------------------------------------------------------------------------
// 5) out = ctx @ Wo + bo  (f32 out)
// ---------------------------------------------------------------------------
__global__ __launch_bounds__(256) void k_gemm_out(const unsigned short* __restrict__ A,
                                                  const unsigned short* __restrict__ Bt,
                                                  float* __restrict__ out,
                                                  const float* __restrict__ bo){
  __shared__ __align__(16) unsigned short As[128*32];
  __shared__ __align__(16) unsigned short Bs[128*32];
  int t = threadIdx.x;
  int L = t & 63, w = t >> 6;
  int q = L >> 4, c = L & 15;
  int m0 = blockIdx.x * 128, n0 = blockIdx.y * 128;
  int wr = w >> 1, wc = w & 1;
  f32x4 acc[4][4];
  #pragma unroll
  for (int i = 0; i < 4; i++)
    #pragma unroll
    for (int j = 0; j < 4; j++) acc[i][j] = (f32x4){0.f,0.f,0.f,0.f};

  for (int kb = 0; kb < 32; kb++){
    __syncthreads();
    #pragma unroll
    for (int i = 0; i < 2; i++){
      int p = t + i*256;
      int row = p >> 2, cp = p & 3;
      gl2lds16(A  + (m0 + row) * HID + kb*32 + cp*8, As + p*8);
      gl2lds16(Bt + (n0 + row) * HID + kb*32 + cp*8, Bs + p*8);
    }
    __syncthreads();
    s16x8 af[4], bf[4];
    #pragma unroll
    for (int i = 0; i < 4; i++){
      int m = wr*64 + i*16 + c;
      af[i] = *(const s16x8*)(As + m*32 + q*8);
      int n = wc*64 + i*16 + c;
      bf[i] = *(const s16x8*)(Bs + n*32 + q*8);
    }
    #pragma unroll
    for (int i = 0; i < 4; i++)
      #pragma unroll
      for (int j = 0; j < 4; j++)
        acc[i][j] = __builtin_amdgcn_mfma_f32_16x16x32_bf16(af[i], bf[j], acc[i][j], 0, 0, 0);
  }

  #pragma unroll
  for (int j = 0; j < 4; j++){
    int n = n0 + wc*64 + j*16 + c;
    float bv = bo[n];
    #pragma unroll
    for (int i = 0; i < 4; i++){
      int m = m0 + wr*64 + i*16 + q*4;
      #pragma unroll
      for (int r = 0; r < 4; r++)
        out[(size_t)(m + r) * HID + n] = acc[i][j][r] + bv;
    }
  }
}

// ---------------------------------------------------------------------------
extern "C" void kernel_launch(void* const* d_in, const int* in_sizes, int n_in,
                              void* d_out, int out_size, void* d_ws, size_t ws_size,
                              hipStream_t stream){
  const float* hs    = (const float*)d_in[0];
  const int*   amask = (const int*)  d_in[1];
  const float* Wq    = (const float*)d_in[2];
  const float* Wk    = (const float*)d_in[3];
  const float* Wv    = (const float*)d_in[4];
  const float* Wo    = (const float*)d_in[5];
  const float* bo    = (const float*)d_in[6];
  // d_in[7] = alibi: intentionally unused (computed analytically; saves 268 MB of reads)
  float* out = (float*)d_out;

  char* ws = (char*)d_ws;                                        // 48 MB total
  // region 0..16MB: phase-dependent.
  //   phase A (convert/gemm_qkv): Xb bf16 [4096][1024] (0..8M), Wt (8..14M)
  //   phase B (attn/combine):     Part2 f32 [512][64][64] (0..8M),
  //                               L2 f32 [512][64] (8M..), Lsum f32 [32][2048] (8.5M..)
  unsigned short* Xb  = (unsigned short*)(ws);
  unsigned short* Wt  = (unsigned short*)(ws + (8u  << 20));
  unsigned short* Wot = (unsigned short*)(ws + (14u << 20));     // alive until gemm_out
  unsigned short* Qb  = (unsigned short*)(ws + (16u << 20));
  unsigned short* Kb  = (unsigned short*)(ws + (24u << 20));
  unsigned short* Vt  = (unsigned short*)(ws + (32u << 20));     // [b][h][d][s]
  unsigned short* Ctx = (unsigned short*)(ws + (40u << 20));     // Vb temp, then NumBf/ctx
  float* Part2 = (float*)(ws);
  float* L2    = (float*)(ws + (8u << 20));
  float* Lsum  = (float*)(ws + (8u << 20) + (512u << 10));
  unsigned short* Vb = Ctx;   // V in [tok][hd] before transpose; dead after k_transpose_v

  hipLaunchKernelGGL(k_convert_x,  dim3(MTOT*HID/4/256), dim3(256), 0, stream, hs, Xb);
  hipLaunchKernelGGL(k_convert_w,  dim3(16,16,4), dim3(256), 0, stream, Wq, Wk, Wv, Wo, Wt, Wot);
  hipLaunchKernelGGL(k_gemm_qkv,   dim3(32,24),   dim3(256), 0, stream, Xb, Wt, Qb, Kb, Vb);
  hipLaunchKernelGGL(k_transpose_v,dim3(32,32),   dim3(256), 0, stream, Vb, Vt);
  hipLaunchKernelGGL(k_attn,       dim3(48,32),   dim3(256), 0, stream, Qb, Kb, Vt, amask,
                                   Ctx, Lsum, Part2, L2);
  hipLaunchKernelGGL(k_combine,    dim3(MTOT*HID/4/256), dim3(256), 0, stream, Ctx, Lsum, Part2, L2);
  hipLaunchKernelGGL(k_gemm_out,   dim3(32,8),    dim3(256), 0, stream, Ctx, Wot, out, bo);
}